// Round 1
// baseline (1358.774 us; speedup 1.0000x reference)
//
#include <hip/hip_runtime.h>
#include <hip/hip_bf16.h>
#include <hip/hip_fp16.h>
#include <math.h>

// Causal conv via four-step FFT, N = 2T = 131072 = N1(512) x N2(256).
// z = bf16(x) + i*h ; one complex FFT of both real signals.
// ws layout: [0,1MiB) float2 twiddle table tw[m] = exp(-2*pi*i*m/N)
//            [2MiB, 2MiB+256MiB) half2 intermediate buf[seq][col][n1]
// Requires ws_size >= ~258 MiB.

#define TLEN 65536
#define NFFT 131072
#define NN1 512
#define NN2 256
#define ROWS 16

__device__ __forceinline__ float2 cmul(float2 a, float2 b) {
  return make_float2(a.x * b.x - a.y * b.y, a.x * b.y + a.y * b.x);
}

__global__ void k_init_tw(float2* __restrict__ tw) {
  int m = blockIdx.x * 256 + threadIdx.x;
  double ang = (double)m * (-2.0 * 3.14159265358979323846 / (double)NFFT);
  tw[m] = make_float2((float)cos(ang), (float)sin(ang));
}

// K1: forward inner FFT (size 256 over n2, stride 512), twiddle, store half2.
// blockIdx = s*32 + tile, tile covers n1 in [tile*16, tile*16+16).
__global__ __launch_bounds__(256) void k_fwd_inner(
    const float* __restrict__ x, const float* __restrict__ h,
    __half2* __restrict__ buf, const float2* __restrict__ tw) {
  __shared__ float2 tile[ROWS][NN2 + 1];  // +1 complex pad vs bank conflicts
  __shared__ float2 w256[128];
  const int tid = threadIdx.x;
  const int s = blockIdx.x >> 5;
  const int n1base = (blockIdx.x & 31) * ROWS;
  if (tid < 128) w256[tid] = tw[tid * (NFFT / NN2)];
  const float* xp = x + (size_t)s * TLEN;
  const float* hp = h + (size_t)s * TLEN;
  // load: n2 < 128 nonzero (zero padding to 2T), z = bf16(x) + i*h
#pragma unroll
  for (int iter = 0; iter < 2; ++iter) {
    int n2 = iter * 64 + (tid >> 2);
    int n1l = (tid & 3) * 4;
    size_t gi = (size_t)n1base + n1l + (size_t)NN1 * n2;
    float4 xv = *(const float4*)(xp + gi);
    float4 hv = *(const float4*)(hp + gi);
    float xs[4] = {xv.x, xv.y, xv.z, xv.w};
    float hs[4] = {hv.x, hv.y, hv.z, hv.w};
#pragma unroll
    for (int u = 0; u < 4; ++u) {
      float xb = __bfloat162float(__float2bfloat16(xs[u]));
      tile[n1l + u][n2] = make_float2(xb, hs[u]);
    }
  }
  for (int z = tid; z < ROWS * 128; z += 256)
    tile[z >> 7][128 + (z & 127)] = make_float2(0.f, 0.f);
  __syncthreads();
  // 8 radix-2 DIF stages (natural in -> bitrev positions out)
  const int j = tid & 127;
  const int rbase = (tid >> 7) * 8;
#pragma unroll
  for (int st = 0; st < 8; ++st) {
    const int hf = 128 >> st;
    const int pos = j & (hf - 1);
    const int blk = j >> (7 - st);
    const int i0 = (blk << (8 - st)) + pos;
    const float2 w = w256[pos << st];
#pragma unroll
    for (int u = 0; u < 8; ++u) {
      const int r = rbase + u;
      float2 a = tile[r][i0];
      float2 b = tile[r][i0 + hf];
      tile[r][i0] = make_float2(a.x + b.x, a.y + b.y);
      tile[r][i0 + hf] = cmul(make_float2(a.x - b.x, a.y - b.y), w);
    }
    __syncthreads();
  }
  // big twiddle W_N^{n1*k2} (k2 = rev8(position)), store column-major
  __half2* outp = buf + (size_t)s * (NN2 * NN1);
  const int n1l = tid & 15;
  const int n1 = n1base + n1l;
#pragma unroll
  for (int iter = 0; iter < 16; ++iter) {
    int p = iter * 16 + (tid >> 4);
    int k2 = __brev((unsigned)p) >> 24;
    float2 v = cmul(tile[n1l][p], tw[n1 * k2]);
    outp[(size_t)p * NN1 + n1] = __float22half2_rn(v);
  }
}

// K2: per column pair: fwd 512-FFT over n1, Hermitian extract + Y=X*H,
// inverse 512-FFT, conj twiddle + 1/N, in-place.
// blockIdx = s*128 + p. p==0 handles the two self-paired cols (k2=0,128).
__global__ __launch_bounds__(256) void k_mid(
    __half2* __restrict__ buf, const float2* __restrict__ tw) {
  __shared__ float2 colA[NN1], colB[NN1];
  __shared__ float2 w512[256];
  const int tid = threadIdx.x;
  const int s = blockIdx.x >> 7;
  const int p = blockIdx.x & 127;
  int k2a, k2b;
  if (p == 0) { k2a = 0; k2b = 128; } else { k2a = p; k2b = 256 - p; }
  const int cA = __brev((unsigned)k2a) >> 24;  // physical column of logical k2
  const int cB = __brev((unsigned)k2b) >> 24;
  w512[tid] = tw[tid * (NFFT / NN1)];
  __half2* gA = buf + ((size_t)s * NN2 + cA) * NN1;
  __half2* gB = buf + ((size_t)s * NN2 + cB) * NN1;
  for (int u = tid; u < 2 * NN1; u += 256) {
    int col = u >> 9, idx = u & (NN1 - 1);
    float2 f = __half22float2((col ? gB : gA)[idx]);
    (col ? colB : colA)[idx] = f;
  }
  __syncthreads();
  float2* myc = (tid >> 7) ? colB : colA;  // wave-uniform
  const int j = tid & 127;
  // forward DIF 512 (natural n1 in -> bitrev k1 positions)
#pragma unroll
  for (int st = 0; st < 9; ++st) {
    const int hf = 256 >> st;
#pragma unroll
    for (int q = 0; q < 2; ++q) {
      const int bidx = j + q * 128;
      const int pos = bidx & (hf - 1);
      const int blk = bidx >> (8 - st);
      const int i0 = (blk << (9 - st)) + pos;
      const float2 w = w512[pos << st];
      float2 a = myc[i0], b = myc[i0 + hf];
      myc[i0] = make_float2(a.x + b.x, a.y + b.y);
      myc[i0 + hf] = cmul(make_float2(a.x - b.x, a.y - b.y), w);
    }
    __syncthreads();
  }
  // pointwise: X=(Z1+conj Z2)/2, H=-i(Z1-conj Z2)/2, Y=X*H; Y[N-k]=conj(Y[k])
  if (p == 0) {
    if (tid < 128) {
      for (int i = tid; i < 257; i += 128) {  // col k2=0: pairs (k1, 512-k1)
        int jj = (512 - i) & 511;
        int p1 = __brev((unsigned)i) >> 23;
        int p2 = __brev((unsigned)jj) >> 23;
        float2 z1 = colA[p1], z2 = colA[p2];
        float2 X = make_float2(0.5f * (z1.x + z2.x), 0.5f * (z1.y - z2.y));
        float2 H = make_float2(0.5f * (z1.y + z2.y), 0.5f * (z2.x - z1.x));
        float2 Y = cmul(X, H);
        colA[p1] = Y;
        colA[p2] = make_float2(Y.x, -Y.y);
      }
    } else {
      for (int i = tid - 128; i < 256; i += 128) {  // col k2=128: (k1,511-k1)
        int jj = 511 - i;
        int p1 = __brev((unsigned)i) >> 23;
        int p2 = __brev((unsigned)jj) >> 23;
        float2 z1 = colB[p1], z2 = colB[p2];
        float2 X = make_float2(0.5f * (z1.x + z2.x), 0.5f * (z1.y - z2.y));
        float2 H = make_float2(0.5f * (z1.y + z2.y), 0.5f * (z2.x - z1.x));
        float2 Y = cmul(X, H);
        colB[p1] = Y;
        colB[p2] = make_float2(Y.x, -Y.y);
      }
    }
  } else {
    for (int i = tid; i < 512; i += 256) {  // partner of (k1,p) is (511-k1,256-p)
      int jj = 511 - i;
      int p1 = __brev((unsigned)i) >> 23;
      int p2 = __brev((unsigned)jj) >> 23;
      float2 z1 = colA[p1], z2 = colB[p2];
      float2 X = make_float2(0.5f * (z1.x + z2.x), 0.5f * (z1.y - z2.y));
      float2 H = make_float2(0.5f * (z1.y + z2.y), 0.5f * (z2.x - z1.x));
      float2 Y = cmul(X, H);
      colA[p1] = Y;
      colB[p2] = make_float2(Y.x, -Y.y);
    }
  }
  __syncthreads();
  // inverse DIT 512 (bitrev in -> natural n1 out)
#pragma unroll
  for (int st = 0; st < 9; ++st) {
    const int hf = 1 << st;
#pragma unroll
    for (int q = 0; q < 2; ++q) {
      const int bidx = j + q * 128;
      const int pos = bidx & (hf - 1);
      const int blk = bidx >> st;
      const int i0 = blk * (hf << 1) + pos;
      float2 w = w512[pos << (8 - st)];
      w.y = -w.y;
      float2 a = myc[i0], b = myc[i0 + hf];
      float2 t = cmul(b, w);
      myc[i0] = make_float2(a.x + t.x, a.y + t.y);
      myc[i0 + hf] = make_float2(a.x - t.x, a.y - t.y);
    }
    __syncthreads();
  }
  // conj big twiddle + 1/N, store back in place
  const float invN = 1.0f / (float)NFFT;
  for (int u = tid; u < 2 * NN1; u += 256) {
    int col = u >> 9, n1 = u & (NN1 - 1);
    int k2 = col ? k2b : k2a;
    float2 w = tw[n1 * k2];
    w.y = -w.y;
    float2 v = cmul((col ? colB : colA)[n1], w);
    (col ? gB : gA)[n1] = __float22half2_rn(make_float2(v.x * invN, v.y * invN));
  }
}

// K3: inverse outer FFT (size 256 over k2, bitrev in -> natural n2),
// write Re(y) for n = n1 + 512*n2, n2 < 128 (causal truncation to T).
__global__ __launch_bounds__(256) void k_inv_outer(
    const __half2* __restrict__ buf, float* __restrict__ out,
    const float2* __restrict__ tw) {
  __shared__ float2 tile[ROWS][NN2 + 1];
  __shared__ float2 w256[128];
  const int tid = threadIdx.x;
  const int s = blockIdx.x >> 5;
  const int n1base = (blockIdx.x & 31) * ROWS;
  if (tid < 128) w256[tid] = tw[tid * (NFFT / NN2)];
  const __half2* gp = buf + (size_t)s * (NN2 * NN1);
  const int n1l = tid & 15;
#pragma unroll
  for (int iter = 0; iter < 16; ++iter) {
    int c = iter * 16 + (tid >> 4);
    tile[n1l][c] = __half22float2(gp[(size_t)c * NN1 + n1base + n1l]);
  }
  __syncthreads();
  const int j = tid & 127;
  const int rbase = (tid >> 7) * 8;
#pragma unroll
  for (int st = 0; st < 8; ++st) {
    const int hf = 1 << st;
    const int pos = j & (hf - 1);
    const int blk = j >> st;
    const int i0 = blk * (hf << 1) + pos;
    float2 w = w256[pos << (7 - st)];
    w.y = -w.y;
#pragma unroll
    for (int u = 0; u < 8; ++u) {
      const int r = rbase + u;
      float2 a = tile[r][i0], b = tile[r][i0 + hf];
      float2 t = cmul(b, w);
      tile[r][i0] = make_float2(a.x + t.x, a.y + t.y);
      tile[r][i0 + hf] = make_float2(a.x - t.x, a.y - t.y);
    }
    __syncthreads();
  }
  float* op = out + (size_t)s * TLEN;
#pragma unroll
  for (int iter = 0; iter < 8; ++iter) {
    int n2 = iter * 16 + (tid >> 4);
    op[(size_t)n2 * NN1 + n1base + n1l] = tile[n1l][n2].x;
  }
}

extern "C" void kernel_launch(void* const* d_in, const int* in_sizes, int n_in,
                              void* d_out, int out_size, void* d_ws, size_t ws_size,
                              hipStream_t stream) {
  (void)n_in; (void)out_size; (void)ws_size;
  const float* x = (const float*)d_in[0];
  const float* h = (const float*)d_in[1];
  float* out = (float*)d_out;
  float2* tw = (float2*)d_ws;
  __half2* buf = (__half2*)((char*)d_ws + (size_t)(2 * 1024 * 1024));
  int seqs = in_sizes[0] / TLEN;  // 8*64 = 512
  k_init_tw<<<NFFT / 256, 256, 0, stream>>>(tw);
  k_fwd_inner<<<seqs * 32, 256, 0, stream>>>(x, h, buf, tw);
  k_mid<<<seqs * 128, 256, 0, stream>>>(buf, tw);
  k_inv_outer<<<seqs * 32, 256, 0, stream>>>(buf, out, tw);
}

// Round 2
// 936.587 us; speedup vs baseline: 1.4508x; 1.4508x over previous
//
#include <hip/hip_runtime.h>
#include <hip/hip_bf16.h>
#include <hip/hip_fp16.h>
#include <math.h>

// Causal conv via four-step FFT, N = 2T = 131072 = N1(512) x N2(256).
// z = bf16(x) + i*h ; one complex FFT of both real signals.
// ws layout: [0,1MiB) float2 twiddle table tw[m] = exp(-2*pi*i*m/N)
//            [2MiB, 2MiB+256MiB) half2 intermediate buf[seq][col][n1]

#define TLEN 65536
#define NFFT 131072
#define NN1 512
#define NN2 256
#define ROWS 16

#define WFENCE() asm volatile("s_waitcnt lgkmcnt(0)" ::: "memory")

__device__ __forceinline__ float2 cmul(float2 a, float2 b) {
  return make_float2(a.x * b.x - a.y * b.y, a.x * b.y + a.y * b.x);
}
__device__ __forceinline__ float2 cadd(float2 a, float2 b) { return make_float2(a.x + b.x, a.y + b.y); }
__device__ __forceinline__ float2 csub(float2 a, float2 b) { return make_float2(a.x - b.x, a.y - b.y); }

// out[j] = sum_k in[k] * W8^{S*jk}, W8 = e^{-2pi i/8}; S=-1 fwd, +1 inv. Natural order.
template <int S>
__device__ __forceinline__ void fft8(float2 v[8]) {
  const float C = 0.70710678118654752f;
  const float s = (float)S;
  float2 b0 = cadd(v[0], v[4]), b4 = csub(v[0], v[4]);
  float2 b1 = cadd(v[1], v[5]), d1 = csub(v[1], v[5]);
  float2 b2 = cadd(v[2], v[6]), d2 = csub(v[2], v[6]);
  float2 b3 = cadd(v[3], v[7]), d3 = csub(v[3], v[7]);
  float2 b5 = make_float2(C * (d1.x - s * d1.y), C * (s * d1.x + d1.y));
  float2 b6 = make_float2(-s * d2.y, s * d2.x);
  float2 b7 = make_float2(C * (-d3.x - s * d3.y), C * (s * d3.x - d3.y));
  float2 c0 = cadd(b0, b2), c2 = csub(b0, b2);
  float2 c1 = cadd(b1, b3), e3 = csub(b1, b3);
  float2 c3 = make_float2(-s * e3.y, s * e3.x);
  float2 c4 = cadd(b4, b6), c6 = csub(b4, b6);
  float2 c5 = cadd(b5, b7), e7 = csub(b5, b7);
  float2 c7 = make_float2(-s * e7.y, s * e7.x);
  v[0] = cadd(c0, c1); v[4] = csub(c0, c1);
  v[2] = cadd(c2, c3); v[6] = csub(c2, c3);
  v[1] = cadd(c4, c5); v[5] = csub(c4, c5);
  v[3] = cadd(c6, c7); v[7] = csub(c6, c7);
}

__global__ void k_init_tw(float2* __restrict__ tw) {
  int m = blockIdx.x * 256 + threadIdx.x;
  double ang = (double)m * (-2.0 * 3.14159265358979323846 / (double)NFFT);
  tw[m] = make_float2((float)cos(ang), (float)sin(ang));
}

// K1: forward inner FFT (size 256 over n2, stride 512), twiddle, store half2.
__global__ __launch_bounds__(256) void k_fwd_inner(
    const float* __restrict__ x, const float* __restrict__ h,
    __half2* __restrict__ buf, const float2* __restrict__ tw) {
  __shared__ float2 tile[ROWS][NN2 + 1];
  __shared__ float2 w256[128];
  const int tid = threadIdx.x;
  const int s = blockIdx.x >> 5;
  const int n1base = (blockIdx.x & 31) * ROWS;
  if (tid < 128) w256[tid] = tw[tid * (NFFT / NN2)];
  const float* xp = x + (size_t)s * TLEN;
  const float* hp = h + (size_t)s * TLEN;
#pragma unroll
  for (int iter = 0; iter < 2; ++iter) {
    int n2 = iter * 64 + (tid >> 2);
    int n1l = (tid & 3) * 4;
    size_t gi = (size_t)n1base + n1l + (size_t)NN1 * n2;
    float4 xv = *(const float4*)(xp + gi);
    float4 hv = *(const float4*)(hp + gi);
    float xs[4] = {xv.x, xv.y, xv.z, xv.w};
    float hs[4] = {hv.x, hv.y, hv.z, hv.w};
#pragma unroll
    for (int u = 0; u < 4; ++u) {
      float xb = __bfloat162float(__float2bfloat16(xs[u]));
      tile[n1l + u][n2] = make_float2(xb, hs[u]);
    }
  }
  for (int z = tid; z < ROWS * 128; z += 256)
    tile[z >> 7][128 + (z & 127)] = make_float2(0.f, 0.f);
  __syncthreads();
  const int j = tid & 127;
  const int rbase = (tid >> 7) * 8;
#pragma unroll
  for (int st = 0; st < 8; ++st) {
    const int hf = 128 >> st;
    const int pos = j & (hf - 1);
    const int blk = j >> (7 - st);
    const int i0 = (blk << (8 - st)) + pos;
    const float2 w = w256[pos << st];
#pragma unroll
    for (int u = 0; u < 8; ++u) {
      const int r = rbase + u;
      float2 a = tile[r][i0];
      float2 b = tile[r][i0 + hf];
      tile[r][i0] = make_float2(a.x + b.x, a.y + b.y);
      tile[r][i0 + hf] = cmul(make_float2(a.x - b.x, a.y - b.y), w);
    }
    __syncthreads();
  }
  __half2* outp = buf + (size_t)s * (NN2 * NN1);
  const int n1l = tid & 15;
  const int n1 = n1base + n1l;
#pragma unroll
  for (int iter = 0; iter < 16; ++iter) {
    int p = iter * 16 + (tid >> 4);
    int k2 = __brev((unsigned)p) >> 24;
    float2 v = cmul(tile[n1l][p], tw[n1 * k2]);
    outp[(size_t)p * NN1 + n1] = __float22half2_rn(v);
  }
}

// K2 (rewritten): register radix-8 Stockham. One wave per 512-column.
// Block = 4 waves = 2 column pairs. blockIdx = s*64 + pb, pairs (2pb, 2pb+1).
// Per-wave scratch region: 576 complex. Layouts:
//   exch1: phys = 64*j + (l ^ 8j)            (XOR swizzle, conflict-free W+R)
//   exch2: phys = 9*(8j + r0) + m0           (stride-9 rows, conflict-free W+R)
//   natural: phys = c + (c>>3)               (pad-8; write/partner/gather all ~free)
// Intra-wave exchanges: DS ops in-order per wave + s_waitcnt lgkmcnt(0); no barrier.
__global__ __launch_bounds__(256, 6) void k_mid(
    __half2* __restrict__ buf, const float2* __restrict__ tw) {
  __shared__ float2 smem[4 * 576 + 512];
  float2* w512 = smem + 4 * 576;
  const int tid = threadIdx.x;
  const int lane = tid & 63;
  const int wid = tid >> 6;
  const int s = blockIdx.x >> 6;
  const int pb = blockIdx.x & 63;
  for (int i = tid; i < 512; i += 256) w512[i] = tw[i * (NFFT / NN1)];
  const int p = 2 * pb + (wid >> 1);
  const int cidx = wid & 1;
  const int k2 = (p == 0) ? (cidx ? 128 : 0) : (cidx ? 256 - p : p);
  const int c = __brev((unsigned)k2) >> 24;
  const bool selfA = (p == 0 && cidx == 0);
  float2* R = smem + wid * 576;
  float2* PR = smem + ((p == 0) ? wid : (wid ^ 1)) * 576;
  __half2* colp = buf + ((size_t)s * NN2 + c) * NN1;

  float2 v[8];
#pragma unroll
  for (int k = 0; k < 8; ++k) v[k] = __half22float2(colp[lane + 64 * k]);
  __syncthreads();  // w512 table ready

  const int jm = lane >> 3, mo = lane & 7;
  const int kbase = jm + 8 * mo;

  // ---------- forward 512 (natural n -> natural k) ----------
  fft8<-1>(v);
  {
    float2 w1 = w512[lane];  // W512^l
    float2 pw = w1;
#pragma unroll
    for (int j = 1; j < 8; ++j) { v[j] = cmul(v[j], pw); pw = cmul(pw, w1); }
  }
#pragma unroll
  for (int j = 0; j < 8; ++j) R[64 * j + (lane ^ (8 * j))] = v[j];
  WFENCE();
#pragma unroll
  for (int m1 = 0; m1 < 8; ++m1) v[m1] = R[64 * jm + ((mo + 8 * m1) ^ (8 * jm))];
  fft8<-1>(v);
  {
    float2 w1 = w512[8 * mo];  // W64^{m0}
    float2 pw = w1;
#pragma unroll
    for (int r0 = 1; r0 < 8; ++r0) { v[r0] = cmul(v[r0], pw); pw = cmul(pw, w1); }
  }
  WFENCE();
#pragma unroll
  for (int r0 = 0; r0 < 8; ++r0) R[9 * (8 * jm + r0) + mo] = v[r0];
  WFENCE();
#pragma unroll
  for (int m0 = 0; m0 < 8; ++m0) v[m0] = R[9 * lane + m0];
  fft8<-1>(v);  // v[r1] = F[kbase + 64*r1]

  // ---------- pointwise: X=(Z1+conj Z2)/2, H=-i(Z1-conj Z2)/2, Y=X*H ----------
  WFENCE();
#pragma unroll
  for (int r1 = 0; r1 < 8; ++r1) { int k = kbase + 64 * r1; R[k + (k >> 3)] = v[r1]; }
  __syncthreads();
  float2 z2[8];
#pragma unroll
  for (int r1 = 0; r1 < 8; ++r1) {
    int k = kbase + 64 * r1;
    int pk = selfA ? ((512 - k) & 511) : (511 - k);
    z2[r1] = PR[pk + (pk >> 3)];
  }
  __syncthreads();
#pragma unroll
  for (int r1 = 0; r1 < 8; ++r1) {
    float2 z1 = v[r1], q = z2[r1];
    float2 X = make_float2(0.5f * (z1.x + q.x), 0.5f * (z1.y - q.y));
    float2 H = make_float2(0.5f * (z1.y + q.y), 0.5f * (q.x - z1.x));
    v[r1] = cmul(X, H);
  }
#pragma unroll
  for (int r1 = 0; r1 < 8; ++r1) { int k = kbase + 64 * r1; R[k + (k >> 3)] = v[r1]; }
  WFENCE();
#pragma unroll
  for (int kk = 0; kk < 8; ++kk) { int ci = lane + 64 * kk; v[kk] = R[ci + (ci >> 3)]; }

  // ---------- inverse 512 (natural k -> natural n), conj twiddles ----------
  fft8<1>(v);
  {
    float2 w1 = w512[lane]; w1.y = -w1.y;
    float2 pw = w1;
#pragma unroll
    for (int j = 1; j < 8; ++j) { v[j] = cmul(v[j], pw); pw = cmul(pw, w1); }
  }
  WFENCE();
#pragma unroll
  for (int j = 0; j < 8; ++j) R[64 * j + (lane ^ (8 * j))] = v[j];
  WFENCE();
#pragma unroll
  for (int m1 = 0; m1 < 8; ++m1) v[m1] = R[64 * jm + ((mo + 8 * m1) ^ (8 * jm))];
  fft8<1>(v);
  {
    float2 w1 = w512[8 * mo]; w1.y = -w1.y;
    float2 pw = w1;
#pragma unroll
    for (int r0 = 1; r0 < 8; ++r0) { v[r0] = cmul(v[r0], pw); pw = cmul(pw, w1); }
  }
  WFENCE();
#pragma unroll
  for (int r0 = 0; r0 < 8; ++r0) R[9 * (8 * jm + r0) + mo] = v[r0];
  WFENCE();
#pragma unroll
  for (int m0 = 0; m0 < 8; ++m0) v[m0] = R[9 * lane + m0];
  fft8<1>(v);  // v[r1] = y512[kbase + 64*r1] (unnormalized)

  // ---------- conj big twiddle * 1/N, natural LDS bounce, coalesced store ----------
  const float invN = 1.0f / (float)NFFT;
  const float w0 = 6.28318530717958647692f / (float)NFFT;
  WFENCE();
#pragma unroll
  for (int r1 = 0; r1 < 8; ++r1) {
    int n1 = kbase + 64 * r1;
    float ang = (float)(n1 * k2) * w0;
    float sn, cs;
    __sincosf(ang, &sn, &cs);
    float2 y = cmul(v[r1], make_float2(cs, sn));  // * conj(W_N^{n1*k2}) = e^{+i ang}
    R[n1 + (n1 >> 3)] = make_float2(y.x * invN, y.y * invN);
  }
  WFENCE();
#pragma unroll
  for (int u = 0; u < 8; ++u) {
    int ci = lane + 64 * u;
    colp[ci] = __float22half2_rn(R[ci + (ci >> 3)]);
  }
}

// K3: inverse outer FFT (size 256 over k2, bitrev in -> natural n2),
// write Re(y) for n = n1 + 512*n2, n2 < 128.
__global__ __launch_bounds__(256) void k_inv_outer(
    const __half2* __restrict__ buf, float* __restrict__ out,
    const float2* __restrict__ tw) {
  __shared__ float2 tile[ROWS][NN2 + 1];
  __shared__ float2 w256[128];
  const int tid = threadIdx.x;
  const int s = blockIdx.x >> 5;
  const int n1base = (blockIdx.x & 31) * ROWS;
  if (tid < 128) w256[tid] = tw[tid * (NFFT / NN2)];
  const __half2* gp = buf + (size_t)s * (NN2 * NN1);
  const int n1l = tid & 15;
#pragma unroll
  for (int iter = 0; iter < 16; ++iter) {
    int c = iter * 16 + (tid >> 4);
    tile[n1l][c] = __half22float2(gp[(size_t)c * NN1 + n1base + n1l]);
  }
  __syncthreads();
  const int j = tid & 127;
  const int rbase = (tid >> 7) * 8;
#pragma unroll
  for (int st = 0; st < 8; ++st) {
    const int hf = 1 << st;
    const int pos = j & (hf - 1);
    const int blk = j >> st;
    const int i0 = blk * (hf << 1) + pos;
    float2 w = w256[pos << (7 - st)];
    w.y = -w.y;
#pragma unroll
    for (int u = 0; u < 8; ++u) {
      const int r = rbase + u;
      float2 a = tile[r][i0], b = tile[r][i0 + hf];
      float2 t = cmul(b, w);
      tile[r][i0] = make_float2(a.x + t.x, a.y + t.y);
      tile[r][i0 + hf] = make_float2(a.x - t.x, a.y - t.y);
    }
    __syncthreads();
  }
  float* op = out + (size_t)s * TLEN;
#pragma unroll
  for (int iter = 0; iter < 8; ++iter) {
    int n2 = iter * 16 + (tid >> 4);
    op[(size_t)n2 * NN1 + n1base + n1l] = tile[n1l][n2].x;
  }
}

extern "C" void kernel_launch(void* const* d_in, const int* in_sizes, int n_in,
                              void* d_out, int out_size, void* d_ws, size_t ws_size,
                              hipStream_t stream) {
  (void)n_in; (void)out_size; (void)ws_size;
  const float* x = (const float*)d_in[0];
  const float* h = (const float*)d_in[1];
  float* out = (float*)d_out;
  float2* tw = (float2*)d_ws;
  __half2* buf = (__half2*)((char*)d_ws + (size_t)(2 * 1024 * 1024));
  int seqs = in_sizes[0] / TLEN;  // 8*64 = 512
  k_init_tw<<<NFFT / 256, 256, 0, stream>>>(tw);
  k_fwd_inner<<<seqs * 32, 256, 0, stream>>>(x, h, buf, tw);
  k_mid<<<seqs * 64, 256, 0, stream>>>(buf, tw);
  k_inv_outer<<<seqs * 32, 256, 0, stream>>>(buf, out, tw);
}

// Round 3
// 682.752 us; speedup vs baseline: 1.9901x; 1.3718x over previous
//
#include <hip/hip_runtime.h>
#include <hip/hip_bf16.h>
#include <hip/hip_fp16.h>
#include <math.h>

// Causal conv via four-step FFT, N = 2T = 131072 = N1(512) x N2(256).
// z = bf16(x) + i*h ; one complex FFT serves both real signals.
// n = n1 + 512*n2 (n1 in [0,512), n2 in [0,256), nonzero n2 < 128).
// buf[seq][k2][n1] half2, k2 NATURAL order (256 rows x 512).
// ws: [0,1MiB) float2 tw[m] = exp(-2pi i m/N); [2MiB,+256MiB) buf.

#define TLEN 65536
#define NFFT 131072
#define NN1 512
#define NN2 256

#define WFENCE() asm volatile("s_waitcnt lgkmcnt(0)" ::: "memory")

__device__ __forceinline__ float2 cmul(float2 a, float2 b) {
  return make_float2(a.x * b.x - a.y * b.y, a.x * b.y + a.y * b.x);
}
__device__ __forceinline__ float2 cadd(float2 a, float2 b) { return make_float2(a.x + b.x, a.y + b.y); }
__device__ __forceinline__ float2 csub(float2 a, float2 b) { return make_float2(a.x - b.x, a.y - b.y); }

// out[k] = sum_j in[j] * W8^{S*jk}, W8 = e^{-2pi i/8}. Natural order.
template <int S>
__device__ __forceinline__ void fft8(float2 v[8]) {
  const float C = 0.70710678118654752f;
  const float s = (float)S;
  float2 b0 = cadd(v[0], v[4]), b4 = csub(v[0], v[4]);
  float2 b1 = cadd(v[1], v[5]), d1 = csub(v[1], v[5]);
  float2 b2 = cadd(v[2], v[6]), d2 = csub(v[2], v[6]);
  float2 b3 = cadd(v[3], v[7]), d3 = csub(v[3], v[7]);
  float2 b5 = make_float2(C * (d1.x - s * d1.y), C * (s * d1.x + d1.y));
  float2 b6 = make_float2(-s * d2.y, s * d2.x);
  float2 b7 = make_float2(C * (-d3.x - s * d3.y), C * (s * d3.x - d3.y));
  float2 c0 = cadd(b0, b2), c2 = csub(b0, b2);
  float2 c1 = cadd(b1, b3), e3 = csub(b1, b3);
  float2 c3 = make_float2(-s * e3.y, s * e3.x);
  float2 c4 = cadd(b4, b6), c6 = csub(b4, b6);
  float2 c5 = cadd(b5, b7), e7 = csub(b5, b7);
  float2 c7 = make_float2(-s * e7.y, s * e7.x);
  v[0] = cadd(c0, c1); v[4] = csub(c0, c1);
  v[2] = cadd(c2, c3); v[6] = csub(c2, c3);
  v[1] = cadd(c4, c5); v[5] = csub(c4, c5);
  v[3] = cadd(c6, c7); v[7] = csub(c6, c7);
}

template <int S>
__device__ __forceinline__ void fft4(float2 v[4]) {
  const float s = (float)S;
  float2 t0 = cadd(v[0], v[2]), t1 = csub(v[0], v[2]);
  float2 t2 = cadd(v[1], v[3]), t3 = csub(v[1], v[3]);
  float2 it3 = make_float2(-s * t3.y, s * t3.x);
  v[0] = cadd(t0, t2); v[2] = csub(t0, t2);
  v[1] = cadd(t1, it3); v[3] = csub(t1, it3);
}

__global__ void k_init_tw(float2* __restrict__ tw) {
  int m = blockIdx.x * 256 + threadIdx.x;
  double ang = (double)m * (-2.0 * 3.14159265358979323846 / (double)NFFT);
  tw[m] = make_float2((float)cos(ang), (float)sin(ang));
}

// ---------------------------------------------------------------------------
// K1: forward FFT-256 over n2 for 16 n1 per block + twiddle W_N^{n1 k2}.
// Register FFT 256 = 8x8x4: fft8(regs), E1, fft8(regs), E2, fft4(regs).
// 2 FFTs/wave (32 lanes x 8 regs), 2 passes x 4 waves = 16 columns.
// ---------------------------------------------------------------------------
__global__ __launch_bounds__(256, 3) void k_fwd_inner(
    const float* __restrict__ x, const float* __restrict__ h,
    __half2* __restrict__ buf, const float2* __restrict__ tw) {
  __shared__ __half2 tz[128 * 18];   // z tile [n2][n1], stride 18 (bank-free cols)
  __shared__ float2 xch[4 * 512];    // per-wave exchange scratch
  __shared__ __half2 to[256 * 17];   // out tile [k2][n1l], stride 17
  __shared__ float2 w256[256];       // W256^e
  const int tid = threadIdx.x;
  const int lane = tid & 63;
  const int wid = tid >> 6;
  const int s = blockIdx.x >> 5;
  const int n1b = (blockIdx.x & 31) * 16;
  w256[tid] = tw[tid * (NFFT / 256)];
  // stage-in: 64B-granule rows (4 lanes x float4)
  const float* xp = x + (size_t)s * TLEN;
  const float* hp = h + (size_t)s * TLEN;
  {
    int a = tid & 3, q = tid >> 2;
#pragma unroll
    for (int iter = 0; iter < 2; ++iter) {
      int n2 = q + 64 * iter;
      size_t gi = (size_t)(n1b + 4 * a) + (size_t)512 * n2;
      float4 xv = *(const float4*)(xp + gi);
      float4 hv = *(const float4*)(hp + gi);
      float xs[4] = {xv.x, xv.y, xv.z, xv.w};
      float hs[4] = {hv.x, hv.y, hv.z, hv.w};
#pragma unroll
      for (int c = 0; c < 4; ++c) {
        float xb = __bfloat162float(__float2bfloat16(xs[c]));
        tz[18 * n2 + 4 * a + c] = __float22half2_rn(make_float2(xb, hs[c]));
      }
    }
  }
  __syncthreads();
  float2* X = xch + wid * 512;
  const int f = lane >> 5;
  const int l5 = lane & 31;
  const int fb = f * 256;
  const int hh = l5 >> 2, bb = l5 & 3;  // stage-B/C lane coords
#pragma unroll
  for (int p2 = 0; p2 < 2; ++p2) {
    const int n1l = 8 * p2 + 2 * wid + f;
    const int n1 = n1b + n1l;
    float2 v[8];
#pragma unroll
    for (int j = 0; j < 4; ++j) v[j] = __half22float2(tz[18 * (32 * j + l5) + n1l]);
#pragma unroll
    for (int j = 4; j < 8; ++j) v[j] = make_float2(0.f, 0.f);
    fft8<-1>(v);  // over j -> k0
    { float2 w1 = w256[l5]; float2 pw = w1;  // W256^{l5*k0}
#pragma unroll
      for (int k0 = 1; k0 < 8; ++k0) { v[k0] = cmul(v[k0], pw); pw = cmul(pw, w1); } }
#pragma unroll
    for (int k0 = 0; k0 < 8; ++k0) X[fb + 32 * k0 + (l5 ^ (4 * k0))] = v[k0];
    WFENCE();
#pragma unroll
    for (int j2 = 0; j2 < 8; ++j2) v[j2] = X[fb + 32 * hh + ((4 * j2 + bb) ^ (4 * hh))];
    fft8<-1>(v);  // over j2 -> k'0   (lane: k0 = hh, t = bb)
    { float2 w1 = w256[8 * bb]; float2 pw = w1;  // W32^{t*k'0}
#pragma unroll
      for (int kp = 1; kp < 8; ++kp) { v[kp] = cmul(v[kp], pw); pw = cmul(pw, w1); } }
    WFENCE();
#pragma unroll
    for (int kp = 0; kp < 8; ++kp) {
      int cc = kp & 3, gg = kp >> 2;
      X[fb + 128 * gg + 32 * cc + 8 * (bb ^ cc) + hh] = v[kp];
    }
    WFENCE();
#pragma unroll
    for (int g = 0; g < 2; ++g) {  // lane: k0 = hh, k'0 = bb + 4g
      float2 u4[4];
#pragma unroll
      for (int t = 0; t < 4; ++t) u4[t] = X[fb + 128 * g + 32 * bb + 8 * (t ^ bb) + hh];
      fft4<-1>(u4);  // over t -> k'1
#pragma unroll
      for (int k1q = 0; k1q < 4; ++k1q) {
        int k2 = hh + 8 * bb + 32 * g + 64 * k1q;
        float ang = (float)(n1 * k2) * (6.28318530717958647692f / (float)NFFT);
        float sn, cs; __sincosf(ang, &sn, &cs);
        float2 y = cmul(u4[k1q], make_float2(cs, -sn));  // * W_N^{n1*k2}
        to[17 * k2 + n1l] = __float22half2_rn(y);
      }
    }
    WFENCE();
  }
  __syncthreads();
  // out: rows k2 natural, 64B granule (4 lanes x 16B)
  {
    int c = tid & 3, q = tid >> 2;
#pragma unroll
    for (int iter = 0; iter < 4; ++iter) {
      int row = q + 64 * iter;
      __half2 h0 = to[17 * row + 4 * c + 0], h1 = to[17 * row + 4 * c + 1];
      __half2 h2 = to[17 * row + 4 * c + 2], h3 = to[17 * row + 4 * c + 3];
      int4 pk;
      pk.x = *(int*)&h0; pk.y = *(int*)&h1; pk.z = *(int*)&h2; pk.w = *(int*)&h3;
      *(int4*)(buf + ((size_t)s * NN2 + row) * NN1 + n1b + 4 * c) = pk;
    }
  }
}

// ---------------------------------------------------------------------------
// K2: per column pair (k2, 256-k2): fwd 512-FFT over n1, Hermitian extract +
// Y=X*H, inverse 512-FFT, conj big twiddle + 1/N, in place. Columns NATURAL.
// ---------------------------------------------------------------------------
__global__ __launch_bounds__(256, 6) void k_mid(
    __half2* __restrict__ buf, const float2* __restrict__ tw) {
  __shared__ float2 smem[4 * 576 + 512];
  float2* w512 = smem + 4 * 576;
  const int tid = threadIdx.x;
  const int lane = tid & 63;
  const int wid = tid >> 6;
  const int s = blockIdx.x >> 6;
  const int pb = blockIdx.x & 63;
  for (int i = tid; i < 512; i += 256) w512[i] = tw[i * (NFFT / NN1)];
  const int p = 2 * pb + (wid >> 1);
  const int cidx = wid & 1;
  const int k2 = (p == 0) ? (cidx ? 128 : 0) : (cidx ? 256 - p : p);
  const int c = k2;  // natural rows now
  const bool selfA = (p == 0 && cidx == 0);
  float2* R = smem + wid * 576;
  float2* PR = smem + ((p == 0) ? wid : (wid ^ 1)) * 576;
  __half2* colp = buf + ((size_t)s * NN2 + c) * NN1;

  float2 v[8];
#pragma unroll
  for (int k = 0; k < 8; ++k) v[k] = __half22float2(colp[lane + 64 * k]);
  __syncthreads();  // w512 ready

  const int jm = lane >> 3, mo = lane & 7;
  const int kbase = jm + 8 * mo;

  fft8<-1>(v);
  { float2 w1 = w512[lane]; float2 pw = w1;
#pragma unroll
    for (int j = 1; j < 8; ++j) { v[j] = cmul(v[j], pw); pw = cmul(pw, w1); } }
#pragma unroll
  for (int j = 0; j < 8; ++j) R[64 * j + (lane ^ (8 * j))] = v[j];
  WFENCE();
#pragma unroll
  for (int m1 = 0; m1 < 8; ++m1) v[m1] = R[64 * jm + ((mo + 8 * m1) ^ (8 * jm))];
  fft8<-1>(v);
  { float2 w1 = w512[8 * mo]; float2 pw = w1;
#pragma unroll
    for (int r0 = 1; r0 < 8; ++r0) { v[r0] = cmul(v[r0], pw); pw = cmul(pw, w1); } }
  WFENCE();
#pragma unroll
  for (int r0 = 0; r0 < 8; ++r0) R[9 * (8 * jm + r0) + mo] = v[r0];
  WFENCE();
#pragma unroll
  for (int m0 = 0; m0 < 8; ++m0) v[m0] = R[9 * lane + m0];
  fft8<-1>(v);  // v[r1] = F[kbase + 64*r1]

  WFENCE();
#pragma unroll
  for (int r1 = 0; r1 < 8; ++r1) { int k = kbase + 64 * r1; R[k + (k >> 3)] = v[r1]; }
  __syncthreads();
  float2 z2[8];
#pragma unroll
  for (int r1 = 0; r1 < 8; ++r1) {
    int k = kbase + 64 * r1;
    int pk = selfA ? ((512 - k) & 511) : (511 - k);
    z2[r1] = PR[pk + (pk >> 3)];
  }
  __syncthreads();
#pragma unroll
  for (int r1 = 0; r1 < 8; ++r1) {
    float2 z1 = v[r1], q = z2[r1];
    float2 Xf = make_float2(0.5f * (z1.x + q.x), 0.5f * (z1.y - q.y));
    float2 Hf = make_float2(0.5f * (z1.y + q.y), 0.5f * (q.x - z1.x));
    v[r1] = cmul(Xf, Hf);
  }
#pragma unroll
  for (int r1 = 0; r1 < 8; ++r1) { int k = kbase + 64 * r1; R[k + (k >> 3)] = v[r1]; }
  WFENCE();
#pragma unroll
  for (int kk = 0; kk < 8; ++kk) { int ci = lane + 64 * kk; v[kk] = R[ci + (ci >> 3)]; }

  fft8<1>(v);
  { float2 w1 = w512[lane]; w1.y = -w1.y; float2 pw = w1;
#pragma unroll
    for (int j = 1; j < 8; ++j) { v[j] = cmul(v[j], pw); pw = cmul(pw, w1); } }
  WFENCE();
#pragma unroll
  for (int j = 0; j < 8; ++j) R[64 * j + (lane ^ (8 * j))] = v[j];
  WFENCE();
#pragma unroll
  for (int m1 = 0; m1 < 8; ++m1) v[m1] = R[64 * jm + ((mo + 8 * m1) ^ (8 * jm))];
  fft8<1>(v);
  { float2 w1 = w512[8 * mo]; w1.y = -w1.y; float2 pw = w1;
#pragma unroll
    for (int r0 = 1; r0 < 8; ++r0) { v[r0] = cmul(v[r0], pw); pw = cmul(pw, w1); } }
  WFENCE();
#pragma unroll
  for (int r0 = 0; r0 < 8; ++r0) R[9 * (8 * jm + r0) + mo] = v[r0];
  WFENCE();
#pragma unroll
  for (int m0 = 0; m0 < 8; ++m0) v[m0] = R[9 * lane + m0];
  fft8<1>(v);  // y512[kbase + 64*r1], unnormalized

  const float invN = 1.0f / (float)NFFT;
  const float w0 = 6.28318530717958647692f / (float)NFFT;
  WFENCE();
#pragma unroll
  for (int r1 = 0; r1 < 8; ++r1) {
    int n1 = kbase + 64 * r1;
    float ang = (float)(n1 * k2) * w0;
    float sn, cs; __sincosf(ang, &sn, &cs);
    float2 y = cmul(v[r1], make_float2(cs, sn));  // * conj(W_N^{n1*k2})
    R[n1 + (n1 >> 3)] = make_float2(y.x * invN, y.y * invN);
  }
  WFENCE();
#pragma unroll
  for (int u = 0; u < 8; ++u) {
    int ci = lane + 64 * u;
    colp[ci] = __float22half2_rn(R[ci + (ci >> 3)]);
  }
}

// ---------------------------------------------------------------------------
// K3: inverse FFT-256 over k2 for 16 n1 per block; write Re(y), n2 < 128.
// Exact adjoint-with-conjugate of K1's register FFT.
// ---------------------------------------------------------------------------
__global__ __launch_bounds__(256, 3) void k_inv_outer(
    const __half2* __restrict__ buf, float* __restrict__ out,
    const float2* __restrict__ tw) {
  __shared__ __half2 ti[16 * 257];   // in tile [n1l][k2], stride 257
  __shared__ float2 xch[4 * 512];
  __shared__ float ty[128 * 17];     // y tile [n2][n1l], stride 17
  __shared__ float2 w256[256];
  const int tid = threadIdx.x;
  const int lane = tid & 63;
  const int wid = tid >> 6;
  const int s = blockIdx.x >> 5;
  const int n1b = (blockIdx.x & 31) * 16;
  w256[tid] = tw[tid * (NFFT / 256)];
  // stage-in: rows k2, 64B granule
  {
    int c = tid & 3, q = tid >> 2;
#pragma unroll
    for (int iter = 0; iter < 4; ++iter) {
      int row = q + 64 * iter;
      int4 pk = *(const int4*)(buf + ((size_t)s * NN2 + row) * NN1 + n1b + 4 * c);
      __half2 hv[4];
      *(int*)&hv[0] = pk.x; *(int*)&hv[1] = pk.y; *(int*)&hv[2] = pk.z; *(int*)&hv[3] = pk.w;
#pragma unroll
      for (int j = 0; j < 4; ++j) ti[(4 * c + j) * 257 + row] = hv[j];
    }
  }
  __syncthreads();
  float2* X = xch + wid * 512;
  const int f = lane >> 5;
  const int l5 = lane & 31;
  const int fb = f * 256;
  const int hh = l5 >> 2, bb = l5 & 3;
#pragma unroll
  for (int p2 = 0; p2 < 2; ++p2) {
    const int n1l = 8 * p2 + 2 * wid + f;
    // load k-layout: k = hh + 8bb + 32g + 64k'1
    float2 v2[2][4];
#pragma unroll
    for (int g = 0; g < 2; ++g)
#pragma unroll
      for (int k1q = 0; k1q < 4; ++k1q)
        v2[g][k1q] = __half22float2(ti[n1l * 257 + hh + 8 * bb + 32 * g + 64 * k1q]);
    // ifft4 over k'1 -> t
#pragma unroll
    for (int g = 0; g < 2; ++g) fft4<1>(v2[g]);
    // E2^T: write stage-C layout -> scratch
#pragma unroll
    for (int g = 0; g < 2; ++g)
#pragma unroll
      for (int t = 0; t < 4; ++t)
        X[fb + 128 * g + 32 * bb + 8 * (t ^ bb) + hh] = v2[g][t];
    WFENCE();
    float2 v[8];
#pragma unroll
    for (int kp = 0; kp < 8; ++kp) {
      int cc = kp & 3, gg = kp >> 2;
      v[kp] = X[fb + 128 * gg + 32 * cc + 8 * (bb ^ cc) + hh];  // lane: k0=hh, t=bb
    }
    { float2 w1 = w256[8 * bb]; w1.y = -w1.y; float2 pw = w1;  // conj W32^{t*k'0}
#pragma unroll
      for (int kp = 1; kp < 8; ++kp) { v[kp] = cmul(v[kp], pw); pw = cmul(pw, w1); } }
    fft8<1>(v);  // over k'0 -> j2
    WFENCE();
#pragma unroll
    for (int j2 = 0; j2 < 8; ++j2) X[fb + 32 * hh + ((4 * j2 + bb) ^ (4 * hh))] = v[j2];
    WFENCE();
#pragma unroll
    for (int k0 = 0; k0 < 8; ++k0) v[k0] = X[fb + 32 * k0 + (l5 ^ (4 * k0))];
    { float2 w1 = w256[l5]; w1.y = -w1.y; float2 pw = w1;  // conj W256^{l5*k0}
#pragma unroll
      for (int k0 = 1; k0 < 8; ++k0) { v[k0] = cmul(v[k0], pw); pw = cmul(pw, w1); } }
    fft8<1>(v);  // over k0 -> j : v[j] = y[32j + l5]
#pragma unroll
    for (int j = 0; j < 4; ++j) ty[17 * (32 * j + l5) + n1l] = v[j].x;
    WFENCE();
  }
  __syncthreads();
  // out: y[n1 + 512*n2], n2 < 128; 2 lanes x 32B = 64B rows
  {
    int e = tid & 1, n2 = tid >> 1;
    float* op = out + (size_t)s * TLEN + (size_t)512 * n2 + n1b + 8 * e;
    float4 o0, o1;
    o0.x = ty[17 * n2 + 8 * e + 0]; o0.y = ty[17 * n2 + 8 * e + 1];
    o0.z = ty[17 * n2 + 8 * e + 2]; o0.w = ty[17 * n2 + 8 * e + 3];
    o1.x = ty[17 * n2 + 8 * e + 4]; o1.y = ty[17 * n2 + 8 * e + 5];
    o1.z = ty[17 * n2 + 8 * e + 6]; o1.w = ty[17 * n2 + 8 * e + 7];
    *(float4*)op = o0;
    *(float4*)(op + 4) = o1;
  }
}

extern "C" void kernel_launch(void* const* d_in, const int* in_sizes, int n_in,
                              void* d_out, int out_size, void* d_ws, size_t ws_size,
                              hipStream_t stream) {
  (void)n_in; (void)out_size; (void)ws_size;
  const float* x = (const float*)d_in[0];
  const float* h = (const float*)d_in[1];
  float* out = (float*)d_out;
  float2* tw = (float2*)d_ws;
  __half2* buf = (__half2*)((char*)d_ws + (size_t)(2 * 1024 * 1024));
  int seqs = in_sizes[0] / TLEN;  // 8*64 = 512
  k_init_tw<<<NFFT / 256, 256, 0, stream>>>(tw);
  k_fwd_inner<<<seqs * 32, 256, 0, stream>>>(x, h, buf, tw);
  k_mid<<<seqs * 64, 256, 0, stream>>>(buf, tw);
  k_inv_outer<<<seqs * 32, 256, 0, stream>>>(buf, out, tw);
}